// Round 1
// baseline (74.755 us; speedup 1.0000x reference)
//
#include <hip/hip_runtime.h>
#include <hip/hip_bf16.h>

// ---- problem constants ----
// B=128, D=1024, ADA=1024, R=8, 4*D*R=32768

typedef __attribute__((ext_vector_type(8))) __bf16 bf16x8;
typedef __attribute__((ext_vector_type(8))) short short8v;
typedef __attribute__((ext_vector_type(4))) float f32x4;

__device__ __forceinline__ float gelu_exact(float v) {
    return 0.5f * v * (1.0f + erff(v * 0.7071067811865476f));
}
__device__ __forceinline__ unsigned short f2bf(float f) {
    union { float f; unsigned u; } c; c.f = f;
    return (unsigned short)((c.u + 0x7FFFu + ((c.u >> 16) & 1u)) >> 16);
}

// ---------- LayerNorm(ada_emb) -> c_bf16 ; cast x -> x_bf16 ----------
__global__ __launch_bounds__(256) void ln_cast_kernel(
    const float* __restrict__ ada, const float* __restrict__ g, const float* __restrict__ be,
    const float* __restrict__ x, unsigned short* __restrict__ cbf, unsigned short* __restrict__ xbf)
{
    int b = blockIdx.x, t = threadIdx.x;
    float4 v = ((const float4*)(ada + b * 1024))[t];
    float s  = v.x + v.y + v.z + v.w;
    float ss = v.x*v.x + v.y*v.y + v.z*v.z + v.w*v.w;
    #pragma unroll
    for (int off = 32; off; off >>= 1) { s += __shfl_xor(s, off); ss += __shfl_xor(ss, off); }
    __shared__ float rs[4], rss[4];
    int wid = t >> 6;
    if ((t & 63) == 0) { rs[wid] = s; rss[wid] = ss; }
    __syncthreads();
    float S  = rs[0] + rs[1] + rs[2] + rs[3];
    float SS = rss[0] + rss[1] + rss[2] + rss[3];
    float mu = S * (1.0f / 1024.0f);
    float rstd = rsqrtf(SS * (1.0f / 1024.0f) - mu * mu + 1e-5f);
    float4 gv = ((const float4*)g)[t];
    float4 bv = ((const float4*)be)[t];
    ushort4 o;
    o.x = f2bf((v.x - mu) * rstd * gv.x + bv.x);
    o.y = f2bf((v.y - mu) * rstd * gv.y + bv.y);
    o.z = f2bf((v.z - mu) * rstd * gv.z + bv.z);
    o.w = f2bf((v.w - mu) * rstd * gv.w + bv.w);
    ((ushort4*)(cbf + b * 1024))[t] = o;
    float4 xv = ((const float4*)(x + b * 1024))[t];
    ushort4 xo;
    xo.x = f2bf(xv.x); xo.y = f2bf(xv.y); xo.z = f2bf(xv.z); xo.w = f2bf(xv.w);
    ((ushort4*)(xbf + b * 1024))[t] = xo;
}

// ---------- MFMA GEMM: C[128 x N] = A[128 x K](bf16) * B(f32->bf16) ----------
// BT=false: B accessed as B[k][n] (row-major, ld=ldb)
// BT=true : B accessed as B[k][n] = Bsrc[n][k] (i.e. C = A * Bsrc^T)
// Grid: (N/64, splits). Each split writes its own partial slab (deterministic).
template <bool BT>
__global__ __launch_bounds__(256, 2) void gemm_kernel(
    const unsigned short* __restrict__ A, const float* __restrict__ Bm,
    float* __restrict__ C, const float* __restrict__ bias,
    int ldb, int ldc, int kchunk, int partStride)
{
    __shared__ __align__(16) unsigned short As[128 * 72];
    __shared__ __align__(16) unsigned short Bs[64 * 72];
    const int t = threadIdx.x;
    const int n0 = blockIdx.x * 64;
    const int k0base = blockIdx.y * kchunk;
    float* __restrict__ Cout = C + (size_t)blockIdx.y * partStride;

    const int lane = t & 63, wid = t >> 6;
    const int wm = wid >> 1, wn = wid & 1;
    const int q = lane >> 4, c16 = lane & 15;

    f32x4 acc[4][2] = {};

    const int nsteps = kchunk >> 6;
    for (int kk = 0; kk < nsteps; ++kk) {
        const int k0 = k0base + (kk << 6);
        // ---- stage A tile [128 m][64 k] bf16
        {
            const int row = t >> 1, half = t & 1;
            const unsigned short* src = A + row * 1024 + k0 + half * 32;
            unsigned short* dst = As + row * 72 + half * 32;
            #pragma unroll
            for (int c2 = 0; c2 < 4; ++c2)
                *(short8v*)(dst + c2 * 8) = *(const short8v*)(src + c2 * 8);
        }
        // ---- stage B tile into k-major Bs[n][k] (64 n rows x 64 k)
        if (!BT) {
            const int np = t & 31, kc = t >> 5;
            const float* src = Bm + (size_t)(k0 + kc * 8) * ldb + n0 + np * 2;
            short8v s0, s1;
            #pragma unroll
            for (int i = 0; i < 8; ++i) {
                float2 f = *(const float2*)(src + (size_t)i * ldb);
                s0[i] = (short)f2bf(f.x);
                s1[i] = (short)f2bf(f.y);
            }
            *(short8v*)(Bs + (np * 2 + 0) * 72 + kc * 8) = s0;
            *(short8v*)(Bs + (np * 2 + 1) * 72 + kc * 8) = s1;
        } else {
            const int nr = t >> 2, part = t & 3;
            const float* src = Bm + (size_t)(n0 + nr) * ldb + k0 + part * 16;
            short8v s0, s1;
            #pragma unroll
            for (int c4 = 0; c4 < 2; ++c4) {
                float4 f = *(const float4*)(src + c4 * 4);
                s0[c4 * 4 + 0] = (short)f2bf(f.x); s0[c4 * 4 + 1] = (short)f2bf(f.y);
                s0[c4 * 4 + 2] = (short)f2bf(f.z); s0[c4 * 4 + 3] = (short)f2bf(f.w);
            }
            #pragma unroll
            for (int c4 = 0; c4 < 2; ++c4) {
                float4 f = *(const float4*)(src + 8 + c4 * 4);
                s1[c4 * 4 + 0] = (short)f2bf(f.x); s1[c4 * 4 + 1] = (short)f2bf(f.y);
                s1[c4 * 4 + 2] = (short)f2bf(f.z); s1[c4 * 4 + 3] = (short)f2bf(f.w);
            }
            *(short8v*)(Bs + nr * 72 + part * 16) = s0;
            *(short8v*)(Bs + nr * 72 + part * 16 + 8) = s1;
        }
        __syncthreads();
        // ---- compute: 2 x k32 mfma steps
        #pragma unroll
        for (int ks = 0; ks < 64; ks += 32) {
            bf16x8 af[4], bfv[2];
            #pragma unroll
            for (int mt = 0; mt < 4; ++mt)
                af[mt] = __builtin_bit_cast(bf16x8,
                    *(const short8v*)(As + (wm * 64 + mt * 16 + c16) * 72 + ks + q * 8));
            #pragma unroll
            for (int nt = 0; nt < 2; ++nt)
                bfv[nt] = __builtin_bit_cast(bf16x8,
                    *(const short8v*)(Bs + (wn * 32 + nt * 16 + c16) * 72 + ks + q * 8));
            #pragma unroll
            for (int mt = 0; mt < 4; ++mt)
                #pragma unroll
                for (int nt = 0; nt < 2; ++nt)
                    acc[mt][nt] = __builtin_amdgcn_mfma_f32_16x16x32_bf16(
                        af[mt], bfv[nt], acc[mt][nt], 0, 0, 0);
        }
        __syncthreads();
    }
    // ---- store (D frag: col = lane&15, row = (lane>>4)*4 + j)
    #pragma unroll
    for (int mt = 0; mt < 4; ++mt) {
        const int m = wm * 64 + mt * 16 + q * 4;
        #pragma unroll
        for (int nt = 0; nt < 2; ++nt) {
            const int n = n0 + wn * 32 + nt * 16 + c16;
            const float bb = bias ? bias[n] : 0.0f;
            #pragma unroll
            for (int j = 0; j < 4; ++j)
                Cout[(size_t)(m + j) * ldc + n] = acc[mt][nt][j] + bb;
        }
    }
}

// ---------- h = bf16(gelu(sum partials + b1)) ----------
__global__ __launch_bounds__(256) void hgen_kernel(
    const float* __restrict__ P, const float* __restrict__ bias, unsigned short* __restrict__ hbf)
{
    int idx = blockIdx.x * 256 + threadIdx.x;
    float s = bias[idx & 1023];
    #pragma unroll
    for (int p = 0; p < 8; ++p) s += P[p * 131072 + idx];
    hbf[idx] = f2bf(gelu_exact(s));
}

// ---------- t[b,r] = sum_d wchunk[b, d*8+r] * vec[b,d] ----------
__global__ __launch_bounds__(256) void tvec_kernel(
    const float* __restrict__ wch, const float* __restrict__ vec, float* __restrict__ tout)
{
    int b = blockIdx.x, t = threadIdx.x;
    const float* wr = wch + (size_t)b * 32768;
    const float* vr = vec + b * 1024;
    float a[8] = {0, 0, 0, 0, 0, 0, 0, 0};
    for (int d = t; d < 1024; d += 256) {
        float xv = vr[d];
        float4 w0 = *(const float4*)(wr + d * 8);
        float4 w1 = *(const float4*)(wr + d * 8 + 4);
        a[0] += xv * w0.x; a[1] += xv * w0.y; a[2] += xv * w0.z; a[3] += xv * w0.w;
        a[4] += xv * w1.x; a[5] += xv * w1.y; a[6] += xv * w1.z; a[7] += xv * w1.w;
    }
    #pragma unroll
    for (int r = 0; r < 8; ++r)
        #pragma unroll
        for (int off = 32; off; off >>= 1)
            a[r] += __shfl_xor(a[r], off);
    __shared__ float red[4][8];
    if ((t & 63) == 0) {
        #pragma unroll
        for (int r = 0; r < 8; ++r) red[t >> 6][r] = a[r];
    }
    __syncthreads();
    if (t < 8) tout[b * 8 + t] = red[0][t] + red[1][t] + red[2][t] + red[3][t];
}

// ---------- y = gelu(sum partials + lb2 @ t2); write f32 + bf16 ----------
__global__ __launch_bounds__(256) void e1_kernel(
    const float* __restrict__ P, const float* __restrict__ wlb2, const float* __restrict__ t2,
    float* __restrict__ yf, unsigned short* __restrict__ ybf)
{
    int b = blockIdx.x, t = threadIdx.x;
    __shared__ float st[8];
    if (t < 8) st[t] = t2[b * 8 + t];
    __syncthreads();
    for (int l = t; l < 1024; l += 256) {
        int idx = b * 1024 + l;
        float s = 0.0f;
        #pragma unroll
        for (int p = 0; p < 8; ++p) s += P[p * 131072 + idx];
        const float* wr = wlb2 + (size_t)b * 32768 + l * 8;
        float4 w0 = *(const float4*)(wr), w1 = *(const float4*)(wr + 4);
        s += w0.x * st[0] + w0.y * st[1] + w0.z * st[2] + w0.w * st[3]
           + w1.x * st[4] + w1.y * st[5] + w1.z * st[6] + w1.w * st[7];
        float gl = gelu_exact(s);
        yf[idx] = gl;
        ybf[idx] = f2bf(gl);
    }
}

// ---------- out = x + sum partials + la1 @ t1 ----------
__global__ __launch_bounds__(256) void e2_kernel(
    const float* __restrict__ P, const float* __restrict__ wla1, const float* __restrict__ t1,
    const float* __restrict__ x, float* __restrict__ out)
{
    int b = blockIdx.x, t = threadIdx.x;
    __shared__ float st[8];
    if (t < 8) st[t] = t1[b * 8 + t];
    __syncthreads();
    for (int k = t; k < 1024; k += 256) {
        int idx = b * 1024 + k;
        float s = x[idx];
        #pragma unroll
        for (int p = 0; p < 8; ++p) s += P[p * 131072 + idx];
        const float* wr = wla1 + (size_t)b * 32768 + k * 8;
        float4 w0 = *(const float4*)(wr), w1 = *(const float4*)(wr + 4);
        s += w0.x * st[0] + w0.y * st[1] + w0.z * st[2] + w0.w * st[3]
           + w1.x * st[4] + w1.y * st[5] + w1.z * st[6] + w1.w * st[7];
        out[idx] = s;
    }
}

extern "C" void kernel_launch(void* const* d_in, const int* in_sizes, int n_in,
                              void* d_out, int out_size, void* d_ws, size_t ws_size,
                              hipStream_t stream) {
    (void)in_sizes; (void)n_in; (void)out_size; (void)ws_size;
    const float* x        = (const float*)d_in[0];
    const float* ada      = (const float*)d_in[1];
    const float* base_up  = (const float*)d_in[2];
    const float* base_down= (const float*)d_in[3];
    const float* ln_g     = (const float*)d_in[4];
    const float* ln_b     = (const float*)d_in[5];
    const float* W1       = (const float*)d_in[6];
    const float* b1       = (const float*)d_in[7];
    const float* W2       = (const float*)d_in[8];
    const float* b2       = (const float*)d_in[9];

    char* ws = (char*)d_ws;
    float* w            = (float*)(ws + 0);          // 128*32768*4 = 16 MiB
    float* P            = (float*)(ws + 16777216);   // 8*128*1024*4 = 4 MiB
    unsigned short* cbf = (unsigned short*)(ws + 20971520); // 256 KiB
    unsigned short* hbf = (unsigned short*)(ws + 21233664); // 256 KiB
    unsigned short* xbf = (unsigned short*)(ws + 21495808); // 256 KiB
    unsigned short* ybf = (unsigned short*)(ws + 21757952); // 256 KiB
    float* yf           = (float*)(ws + 22020096);   // 512 KiB
    float* t2           = (float*)(ws + 22544384);   // 4 KiB
    float* t1           = (float*)(ws + 22548480);   // 4 KiB

    // 1. LN + casts
    ln_cast_kernel<<<128, 256, 0, stream>>>(ada, ln_g, ln_b, x, cbf, xbf);
    // 2. GEMM1: c @ W1 -> partials (split-K 8)
    gemm_kernel<false><<<dim3(16, 8), 256, 0, stream>>>(cbf, W1, P, nullptr, 1024, 1024, 128, 131072);
    // 3. h = bf16(gelu(sum + b1))
    hgen_kernel<<<512, 256, 0, stream>>>(P, b1, hbf);
    // 4. GEMM2: w = h @ W2 + b2 (direct store)
    gemm_kernel<false><<<dim3(512, 1), 256, 0, stream>>>(hbf, W2, w, b2, 32768, 32768, 1024, 0);
    // 5. t2 = einsum(la2, x)   (la2 = w chunk 2 @ offset 16384)
    tvec_kernel<<<128, 256, 0, stream>>>(w + 16384, x, t2);
    // 6. GEMM3: x @ base_down -> partials
    gemm_kernel<false><<<dim3(16, 8), 256, 0, stream>>>(xbf, base_down, P, nullptr, 1024, 1024, 128, 131072);
    // 7. y = gelu(sum + lb2 @ t2)  (lb2 = chunk 3 @ 24576)
    e1_kernel<<<128, 256, 0, stream>>>(P, w + 24576, t2, yf, ybf);
    // 8. t1 = einsum(lb1, y)   (lb1 = chunk 1 @ 8192)
    tvec_kernel<<<128, 256, 0, stream>>>(w + 8192, yf, t1);
    // 9. GEMM4: y @ base_up^T -> partials
    gemm_kernel<true><<<dim3(16, 8), 256, 0, stream>>>(ybf, base_up, P, nullptr, 1024, 1024, 128, 131072);
    // 10. out = x + sum + la1 @ t1  (la1 = chunk 0)
    e2_kernel<<<128, 256, 0, stream>>>(P, w, t1, x, (float*)d_out);
}

// Round 2
// 59.293 us; speedup vs baseline: 1.2608x; 1.2608x over previous
//
#include <hip/hip_runtime.h>
#include <hip/hip_bf16.h>

// ---- problem constants: B=128, D=1024, ADA=1024, R=8, 4*D*R=32768 ----

typedef __attribute__((ext_vector_type(8))) __bf16 bf16x8;
typedef __attribute__((ext_vector_type(8))) short short8v;
typedef __attribute__((ext_vector_type(4))) float f32x4;

__device__ __forceinline__ float gelu_exact(float v) {
    return 0.5f * v * (1.0f + erff(v * 0.7071067811865476f));
}
__device__ __forceinline__ unsigned short f2bf(float f) {
    union { float f; unsigned u; } c; c.f = f;
    return (unsigned short)((c.u + 0x7FFFu + ((c.u >> 16) & 1u)) >> 16);
}

// ---------- LayerNorm(ada_emb) -> c_bf16 ; cast x -> x_bf16 ----------
__global__ __launch_bounds__(256) void ln_cast_kernel(
    const float* __restrict__ ada, const float* __restrict__ g, const float* __restrict__ be,
    const float* __restrict__ x, unsigned short* __restrict__ cbf, unsigned short* __restrict__ xbf)
{
    int b = blockIdx.x, t = threadIdx.x;
    float4 v = ((const float4*)(ada + b * 1024))[t];
    float s  = v.x + v.y + v.z + v.w;
    float ss = v.x*v.x + v.y*v.y + v.z*v.z + v.w*v.w;
    #pragma unroll
    for (int off = 32; off; off >>= 1) { s += __shfl_xor(s, off); ss += __shfl_xor(ss, off); }
    __shared__ float rs[4], rss[4];
    int wid = t >> 6;
    if ((t & 63) == 0) { rs[wid] = s; rss[wid] = ss; }
    __syncthreads();
    float S  = rs[0] + rs[1] + rs[2] + rs[3];
    float SS = rss[0] + rss[1] + rss[2] + rss[3];
    float mu = S * (1.0f / 1024.0f);
    float rstd = rsqrtf(SS * (1.0f / 1024.0f) - mu * mu + 1e-5f);
    float4 gv = ((const float4*)g)[t];
    float4 bv = ((const float4*)be)[t];
    ushort4 o;
    o.x = f2bf((v.x - mu) * rstd * gv.x + bv.x);
    o.y = f2bf((v.y - mu) * rstd * gv.y + bv.y);
    o.z = f2bf((v.z - mu) * rstd * gv.z + bv.z);
    o.w = f2bf((v.w - mu) * rstd * gv.w + bv.w);
    ((ushort4*)(cbf + b * 1024))[t] = o;
    float4 xv = ((const float4*)(x + b * 1024))[t];
    ushort4 xo;
    xo.x = f2bf(xv.x); xo.y = f2bf(xv.y); xo.z = f2bf(xv.z); xo.w = f2bf(xv.w);
    ((ushort4*)(xbf + b * 1024))[t] = xo;
}

// ---------- MFMA GEMM body: C[128 x *] tile = A[128 x K](bf16) * B(f32->bf16) ----------
// BT=false: B[k][n] row-major (ld=ldb).  BT=true: B[k][n] = Bsrc[n][k]  (C = A * Bsrc^T)
// Software-pipelined: tile k+1 prefetched into registers during tile k's MFMA phase.
template <bool BT>
__device__ __forceinline__ void gemm_body(
    const unsigned short* __restrict__ A, const float* __restrict__ Bm,
    float* __restrict__ C, const float* __restrict__ bias,
    const int ldb, const int ldc, const int kchunk, const int k0base, const int n0)
{
    __shared__ __align__(16) unsigned short As[128 * 72];
    __shared__ __align__(16) unsigned short Bs[64 * 72];
    const int t = threadIdx.x;
    const int lane = t & 63, wid = t >> 6;
    const int wm = wid >> 1, wn = wid & 1;
    const int q = lane >> 4, c16 = lane & 15;

    // A staging map: 2 threads per row, 32 bf16 each
    const int arow = t >> 1, ahalf = t & 1;
    const unsigned short* aptr = A + arow * 1024 + k0base + ahalf * 32;
    unsigned short* adst = As + arow * 72 + ahalf * 32;

    // B staging maps
    const int bnp = t & 31, bkc = t >> 5;   // !BT: thread covers rows [bkc*8, bkc*8+8), cols np*2..+1
    const int bnr = t >> 2, bpart = t & 3;  // BT : thread covers row n0+bnr, k [bpart*16, +16)
    const float* bptr = BT ? (Bm + (size_t)(n0 + bnr) * ldb + k0base + bpart * 16)
                           : (Bm + (size_t)(k0base + bkc * 8) * ldb + n0 + bnp * 2);

    f32x4 acc[4][2] = {};
    short8v ra0, ra1, ra2, ra3;
    float2 rb0, rb1, rb2, rb3, rb4, rb5, rb6, rb7;  // !BT
    float4 rt0, rt1, rt2, rt3;                      // BT

    // prologue: load tile 0 into registers
    ra0 = *(const short8v*)(aptr);      ra1 = *(const short8v*)(aptr + 8);
    ra2 = *(const short8v*)(aptr + 16); ra3 = *(const short8v*)(aptr + 24);
    if (!BT) {
        rb0 = *(const float2*)(bptr);                    rb1 = *(const float2*)(bptr + (size_t)ldb);
        rb2 = *(const float2*)(bptr + (size_t)2 * ldb);  rb3 = *(const float2*)(bptr + (size_t)3 * ldb);
        rb4 = *(const float2*)(bptr + (size_t)4 * ldb);  rb5 = *(const float2*)(bptr + (size_t)5 * ldb);
        rb6 = *(const float2*)(bptr + (size_t)6 * ldb);  rb7 = *(const float2*)(bptr + (size_t)7 * ldb);
    } else {
        rt0 = *(const float4*)(bptr);     rt1 = *(const float4*)(bptr + 4);
        rt2 = *(const float4*)(bptr + 8); rt3 = *(const float4*)(bptr + 12);
    }

    const int nsteps = kchunk >> 6;
    for (int kk = 0; kk < nsteps; ++kk) {
        // ---- registers -> LDS (with f32->bf16 convert for B)
        *(short8v*)(adst)      = ra0; *(short8v*)(adst + 8)  = ra1;
        *(short8v*)(adst + 16) = ra2; *(short8v*)(adst + 24) = ra3;
        if (!BT) {
            short8v s0, s1;
            s0[0]=(short)f2bf(rb0.x); s1[0]=(short)f2bf(rb0.y);
            s0[1]=(short)f2bf(rb1.x); s1[1]=(short)f2bf(rb1.y);
            s0[2]=(short)f2bf(rb2.x); s1[2]=(short)f2bf(rb2.y);
            s0[3]=(short)f2bf(rb3.x); s1[3]=(short)f2bf(rb3.y);
            s0[4]=(short)f2bf(rb4.x); s1[4]=(short)f2bf(rb4.y);
            s0[5]=(short)f2bf(rb5.x); s1[5]=(short)f2bf(rb5.y);
            s0[6]=(short)f2bf(rb6.x); s1[6]=(short)f2bf(rb6.y);
            s0[7]=(short)f2bf(rb7.x); s1[7]=(short)f2bf(rb7.y);
            *(short8v*)(Bs + (bnp * 2 + 0) * 72 + bkc * 8) = s0;
            *(short8v*)(Bs + (bnp * 2 + 1) * 72 + bkc * 8) = s1;
        } else {
            short8v s0, s1;
            s0[0]=(short)f2bf(rt0.x); s0[1]=(short)f2bf(rt0.y); s0[2]=(short)f2bf(rt0.z); s0[3]=(short)f2bf(rt0.w);
            s0[4]=(short)f2bf(rt1.x); s0[5]=(short)f2bf(rt1.y); s0[6]=(short)f2bf(rt1.z); s0[7]=(short)f2bf(rt1.w);
            s1[0]=(short)f2bf(rt2.x); s1[1]=(short)f2bf(rt2.y); s1[2]=(short)f2bf(rt2.z); s1[3]=(short)f2bf(rt2.w);
            s1[4]=(short)f2bf(rt3.x); s1[5]=(short)f2bf(rt3.y); s1[6]=(short)f2bf(rt3.z); s1[7]=(short)f2bf(rt3.w);
            *(short8v*)(Bs + bnr * 72 + bpart * 16)     = s0;
            *(short8v*)(Bs + bnr * 72 + bpart * 16 + 8) = s1;
        }
        __syncthreads();
        // ---- issue prefetch of tile kk+1 (waits land at next iter's LDS writes)
        if (kk + 1 < nsteps) {
            const int koff = (kk + 1) << 6;
            const unsigned short* ap = aptr + koff;
            ra0 = *(const short8v*)(ap);      ra1 = *(const short8v*)(ap + 8);
            ra2 = *(const short8v*)(ap + 16); ra3 = *(const short8v*)(ap + 24);
            if (!BT) {
                const float* bp = bptr + (size_t)koff * ldb;
                rb0 = *(const float2*)(bp);                    rb1 = *(const float2*)(bp + (size_t)ldb);
                rb2 = *(const float2*)(bp + (size_t)2 * ldb);  rb3 = *(const float2*)(bp + (size_t)3 * ldb);
                rb4 = *(const float2*)(bp + (size_t)4 * ldb);  rb5 = *(const float2*)(bp + (size_t)5 * ldb);
                rb6 = *(const float2*)(bp + (size_t)6 * ldb);  rb7 = *(const float2*)(bp + (size_t)7 * ldb);
            } else {
                const float* bp = bptr + koff;
                rt0 = *(const float4*)(bp);     rt1 = *(const float4*)(bp + 4);
                rt2 = *(const float4*)(bp + 8); rt3 = *(const float4*)(bp + 12);
            }
        }
        // ---- MFMA on tile kk
        #pragma unroll
        for (int ks = 0; ks < 64; ks += 32) {
            bf16x8 af[4], bfv[2];
            #pragma unroll
            for (int mt = 0; mt < 4; ++mt)
                af[mt] = __builtin_bit_cast(bf16x8,
                    *(const short8v*)(As + (wm * 64 + mt * 16 + c16) * 72 + ks + q * 8));
            #pragma unroll
            for (int nt = 0; nt < 2; ++nt)
                bfv[nt] = __builtin_bit_cast(bf16x8,
                    *(const short8v*)(Bs + (wn * 32 + nt * 16 + c16) * 72 + ks + q * 8));
            #pragma unroll
            for (int mt = 0; mt < 4; ++mt)
                #pragma unroll
                for (int nt = 0; nt < 2; ++nt)
                    acc[mt][nt] = __builtin_amdgcn_mfma_f32_16x16x32_bf16(
                        af[mt], bfv[nt], acc[mt][nt], 0, 0, 0);
        }
        __syncthreads();
    }
    // ---- store (D frag: col = lane&15, row = (lane>>4)*4 + j)
    #pragma unroll
    for (int mt = 0; mt < 4; ++mt) {
        const int m = wm * 64 + mt * 16 + q * 4;
        #pragma unroll
        for (int nt = 0; nt < 2; ++nt) {
            const int n = n0 + wn * 32 + nt * 16 + c16;
            const float bb = bias ? bias[n] : 0.0f;
            #pragma unroll
            for (int j = 0; j < 4; ++j)
                C[(size_t)(m + j) * ldc + n] = acc[mt][nt][j] + bb;
        }
    }
}

// GEMM1 (c@W1) and GEMM3 (x@base_down) in one launch: grid (16, 8, 2)
__global__ __launch_bounds__(256, 2) void gemm13_kernel(
    const unsigned short* __restrict__ cbf, const float* __restrict__ W1, float* __restrict__ P1,
    const unsigned short* __restrict__ xbf, const float* __restrict__ bdn, float* __restrict__ P2)
{
    const unsigned short* A = blockIdx.z ? xbf : cbf;
    const float* B = blockIdx.z ? bdn : W1;
    float* C = (blockIdx.z ? P2 : P1) + blockIdx.y * 131072;
    gemm_body<false>(A, B, C, nullptr, 1024, 1024, 128, blockIdx.y * 128, blockIdx.x * 64);
}

// GEMM2: w = h @ W2 + b2, direct store, grid (512)
__global__ __launch_bounds__(256, 2) void gemm2_kernel(
    const unsigned short* __restrict__ hbf, const float* __restrict__ W2,
    float* __restrict__ w, const float* __restrict__ b2)
{
    gemm_body<false>(hbf, W2, w, b2, 32768, 32768, 1024, 0, blockIdx.x * 64);
}

// GEMM4: partials of y @ base_up^T, grid (16, 8)
__global__ __launch_bounds__(256, 2) void gemm4_kernel(
    const unsigned short* __restrict__ ybf, const float* __restrict__ bup, float* __restrict__ P1)
{
    gemm_body<true>(ybf, bup, P1 + blockIdx.y * 131072, nullptr, 1024, 1024, 128, blockIdx.y * 128, blockIdx.x * 64);
}

// ---------- h = bf16(gelu(sum partials + b1)) ----------
__global__ __launch_bounds__(256) void hgen_kernel(
    const float* __restrict__ P, const float* __restrict__ bias, unsigned short* __restrict__ hbf)
{
    int idx = blockIdx.x * 256 + threadIdx.x;
    float s = bias[idx & 1023];
    #pragma unroll
    for (int p = 0; p < 8; ++p) s += P[p * 131072 + idx];
    hbf[idx] = f2bf(gelu_exact(s));
}

// ---------- per-row fused epilogue: t2, y=gelu(.), ybf, t1, out_init ----------
__device__ __forceinline__ void block_reduce8(float a[8], float* out8, float (*scr)[8], int t) {
    #pragma unroll
    for (int r = 0; r < 8; ++r)
        #pragma unroll
        for (int off = 32; off; off >>= 1)
            a[r] += __shfl_xor(a[r], off);
    if ((t & 63) == 0) {
        #pragma unroll
        for (int r = 0; r < 8; ++r) scr[t >> 6][r] = a[r];
    }
    __syncthreads();
    if (t < 8) out8[t] = scr[0][t] + scr[1][t] + scr[2][t] + scr[3][t];
    __syncthreads();
}

__global__ __launch_bounds__(256) void e1big_kernel(
    const float* __restrict__ P2, const float* __restrict__ w,
    const float* __restrict__ x, unsigned short* __restrict__ ybf,
    float* __restrict__ out)
{
    __shared__ float scr[4][8];
    __shared__ float t2s[8], t1s[8];
    const int b = blockIdx.x, t = threadIdx.x;
    const float* wrow = w + (size_t)b * 32768;
    const float* xrow = x + b * 1024;

    // stage 1: t2[r] = sum_d la2[b,d,r] * x[b,d]   (la2 = chunk 2 @ +16384)
    float a[8] = {0,0,0,0,0,0,0,0};
    #pragma unroll
    for (int i = 0; i < 4; ++i) {
        int d = t + i * 256;
        float xv = xrow[d];
        float4 w0 = *(const float4*)(wrow + 16384 + d * 8);
        float4 w1 = *(const float4*)(wrow + 16384 + d * 8 + 4);
        a[0] += xv * w0.x; a[1] += xv * w0.y; a[2] += xv * w0.z; a[3] += xv * w0.w;
        a[4] += xv * w1.x; a[5] += xv * w1.y; a[6] += xv * w1.z; a[7] += xv * w1.w;
    }
    block_reduce8(a, t2s, scr, t);
    float t2v[8];
    #pragma unroll
    for (int r = 0; r < 8; ++r) t2v[r] = t2s[r];

    // stage 2: y = gelu(sum P2 + lb2 @ t2); accumulate t1 = sum_l lb1[l,:]*y[l]
    float a1[8] = {0,0,0,0,0,0,0,0};
    #pragma unroll
    for (int i = 0; i < 4; ++i) {
        int l = t + i * 256;
        float s = 0.0f;
        #pragma unroll
        for (int p = 0; p < 8; ++p) s += P2[p * 131072 + b * 1024 + l];
        float4 w0 = *(const float4*)(wrow + 24576 + l * 8);
        float4 w1 = *(const float4*)(wrow + 24576 + l * 8 + 4);
        s += w0.x*t2v[0] + w0.y*t2v[1] + w0.z*t2v[2] + w0.w*t2v[3]
           + w1.x*t2v[4] + w1.y*t2v[5] + w1.z*t2v[6] + w1.w*t2v[7];
        float y = gelu_exact(s);
        ybf[b * 1024 + l] = f2bf(y);
        float4 l0 = *(const float4*)(wrow + 8192 + l * 8);
        float4 l1 = *(const float4*)(wrow + 8192 + l * 8 + 4);
        a1[0] += y * l0.x; a1[1] += y * l0.y; a1[2] += y * l0.z; a1[3] += y * l0.w;
        a1[4] += y * l1.x; a1[5] += y * l1.y; a1[6] += y * l1.z; a1[7] += y * l1.w;
    }
    block_reduce8(a1, t1s, scr, t);
    float t1v[8];
    #pragma unroll
    for (int r = 0; r < 8; ++r) t1v[r] = t1s[r];

    // stage 3: out_init = x + la1 @ t1   (la1 = chunk 0)
    #pragma unroll
    for (int i = 0; i < 4; ++i) {
        int k = t + i * 256;
        float4 w0 = *(const float4*)(wrow + k * 8);
        float4 w1 = *(const float4*)(wrow + k * 8 + 4);
        out[b * 1024 + k] = xrow[k]
           + w0.x*t1v[0] + w0.y*t1v[1] + w0.z*t1v[2] + w0.w*t1v[3]
           + w1.x*t1v[4] + w1.y*t1v[5] + w1.z*t1v[6] + w1.w*t1v[7];
    }
}

// ---------- out += sum GEMM4 partials ----------
__global__ __launch_bounds__(256) void e2f_kernel(
    const float* __restrict__ P1, float* __restrict__ out)
{
    int idx = blockIdx.x * 256 + threadIdx.x;
    float s = out[idx];
    #pragma unroll
    for (int p = 0; p < 8; ++p) s += P1[p * 131072 + idx];
    out[idx] = s;
}

extern "C" void kernel_launch(void* const* d_in, const int* in_sizes, int n_in,
                              void* d_out, int out_size, void* d_ws, size_t ws_size,
                              hipStream_t stream) {
    (void)in_sizes; (void)n_in; (void)out_size; (void)ws_size;
    const float* x        = (const float*)d_in[0];
    const float* ada      = (const float*)d_in[1];
    const float* base_up  = (const float*)d_in[2];
    const float* base_down= (const float*)d_in[3];
    const float* ln_g     = (const float*)d_in[4];
    const float* ln_b     = (const float*)d_in[5];
    const float* W1       = (const float*)d_in[6];
    const float* b1       = (const float*)d_in[7];
    const float* W2       = (const float*)d_in[8];
    const float* b2       = (const float*)d_in[9];

    char* ws = (char*)d_ws;
    float* w            = (float*)(ws + 0);          // 16 MiB
    float* P1           = (float*)(ws + 16777216);   // 4 MiB (GEMM1 partials, reused by GEMM4)
    float* P2           = (float*)(ws + 20971520);   // 4 MiB (GEMM3 partials)
    unsigned short* cbf = (unsigned short*)(ws + 25165824); // 256 KiB
    unsigned short* xbf = (unsigned short*)(ws + 25427968);
    unsigned short* hbf = (unsigned short*)(ws + 25690112);
    unsigned short* ybf = (unsigned short*)(ws + 25952256);

    // 1. LN + bf16 casts
    ln_cast_kernel<<<128, 256, 0, stream>>>(ada, ln_g, ln_b, x, cbf, xbf);
    // 2. GEMM1 (c@W1 -> P1) + GEMM3 (x@base_down -> P2), split-K 8, one launch
    gemm13_kernel<<<dim3(16, 8, 2), 256, 0, stream>>>(cbf, W1, P1, xbf, base_down, P2);
    // 3. h = bf16(gelu(sum P1 + b1))
    hgen_kernel<<<512, 256, 0, stream>>>(P1, b1, hbf);
    // 4. GEMM2: w = h @ W2 + b2
    gemm2_kernel<<<512, 256, 0, stream>>>(hbf, W2, w, b2);
    // 5. fused row epilogue: t2, y, ybf, t1, out = x + la1@t1
    e1big_kernel<<<128, 256, 0, stream>>>(P2, w, x, ybf, (float*)d_out);
    // 6. GEMM4: partials of y @ base_up^T -> P1
    gemm4_kernel<<<dim3(16, 8), 256, 0, stream>>>(ybf, base_up, P1);
    // 7. out += sum partials
    e2f_kernel<<<512, 256, 0, stream>>>(P1, (float*)d_out);
}

// Round 3
// 58.828 us; speedup vs baseline: 1.2707x; 1.0079x over previous
//
#include <hip/hip_runtime.h>
#include <hip/hip_bf16.h>

// ---- problem constants: B=128, D=1024, ADA=1024, R=8, 4*D*R=32768 ----

typedef __attribute__((ext_vector_type(8))) __bf16 bf16x8;
typedef __attribute__((ext_vector_type(8))) short short8v;
typedef __attribute__((ext_vector_type(4))) float f32x4;

__device__ __forceinline__ float gelu_exact(float v) {
    return 0.5f * v * (1.0f + erff(v * 0.7071067811865476f));
}
__device__ __forceinline__ unsigned short f2bf(float f) {
    union { float f; unsigned u; } c; c.f = f;
    return (unsigned short)((c.u + 0x7FFFu + ((c.u >> 16) & 1u)) >> 16);
}

// ---------- LayerNorm(ada_emb) -> c_bf16 ; cast x -> x_bf16 ----------
__global__ __launch_bounds__(256) void ln_cast_kernel(
    const float* __restrict__ ada, const float* __restrict__ g, const float* __restrict__ be,
    const float* __restrict__ x, unsigned short* __restrict__ cbf, unsigned short* __restrict__ xbf)
{
    int b = blockIdx.x, t = threadIdx.x;
    float4 v = ((const float4*)(ada + b * 1024))[t];
    float s  = v.x + v.y + v.z + v.w;
    float ss = v.x*v.x + v.y*v.y + v.z*v.z + v.w*v.w;
    #pragma unroll
    for (int off = 32; off; off >>= 1) { s += __shfl_xor(s, off); ss += __shfl_xor(ss, off); }
    __shared__ float rs[4], rss[4];
    int wid = t >> 6;
    if ((t & 63) == 0) { rs[wid] = s; rss[wid] = ss; }
    __syncthreads();
    float S  = rs[0] + rs[1] + rs[2] + rs[3];
    float SS = rss[0] + rss[1] + rss[2] + rss[3];
    float mu = S * (1.0f / 1024.0f);
    float rstd = rsqrtf(SS * (1.0f / 1024.0f) - mu * mu + 1e-5f);
    float4 gv = ((const float4*)g)[t];
    float4 bv = ((const float4*)be)[t];
    ushort4 o;
    o.x = f2bf((v.x - mu) * rstd * gv.x + bv.x);
    o.y = f2bf((v.y - mu) * rstd * gv.y + bv.y);
    o.z = f2bf((v.z - mu) * rstd * gv.z + bv.z);
    o.w = f2bf((v.w - mu) * rstd * gv.w + bv.w);
    ((ushort4*)(cbf + b * 1024))[t] = o;
    float4 xv = ((const float4*)(x + b * 1024))[t];
    ushort4 xo;
    xo.x = f2bf(xv.x); xo.y = f2bf(xv.y); xo.z = f2bf(xv.z); xo.w = f2bf(xv.w);
    ((ushort4*)(xbf + b * 1024))[t] = xo;
}

// ---------- MFMA GEMM body, LDS double-buffered, 1 barrier / k-step ----------
// C[128 x *] tile = A[128 x K](bf16) * B(f32->bf16)
// BT=false: B[k][n] row-major (ld=ldb).  BT=true: B[k][n] = Bsrc[n][k]  (C = A * Bsrc^T)
template <bool BT>
__device__ __forceinline__ void gemm_body(
    const unsigned short* __restrict__ A, const float* __restrict__ Bm,
    float* __restrict__ C, const float* __restrict__ bias,
    const int ldb, const int ldc, const int kchunk, const int k0base, const int n0)
{
    __shared__ __align__(16) unsigned short As[2][128 * 72];
    __shared__ __align__(16) unsigned short Bs[2][64 * 72];
    const int t = threadIdx.x;
    const int lane = t & 63, wid = t >> 6;
    const int wm = wid >> 1, wn = wid & 1;
    const int q = lane >> 4, c16 = lane & 15;

    // A staging map: 2 threads per row, 32 bf16 each
    const int arow = t >> 1, ahalf = t & 1;
    const unsigned short* aptr = A + arow * 1024 + k0base + ahalf * 32;
    const int adoff = arow * 72 + ahalf * 32;

    // B staging maps
    const int bnp = t & 31, bkc = t >> 5;   // !BT
    const int bnr = t >> 2, bpart = t & 3;  // BT
    const float* bptr = BT ? (Bm + (size_t)(n0 + bnr) * ldb + k0base + bpart * 16)
                           : (Bm + (size_t)(k0base + bkc * 8) * ldb + n0 + bnp * 2);

    f32x4 acc[4][2] = {};
    short8v ra0, ra1, ra2, ra3;
    float2 rb0, rb1, rb2, rb3, rb4, rb5, rb6, rb7;  // !BT
    float4 rt0, rt1, rt2, rt3;                      // BT

    auto LOAD = [&](int kk) {
        const int koff = kk << 6;
        const unsigned short* ap = aptr + koff;
        ra0 = *(const short8v*)(ap);      ra1 = *(const short8v*)(ap + 8);
        ra2 = *(const short8v*)(ap + 16); ra3 = *(const short8v*)(ap + 24);
        if (!BT) {
            const float* bp = bptr + (size_t)koff * ldb;
            rb0 = *(const float2*)(bp);                    rb1 = *(const float2*)(bp + (size_t)ldb);
            rb2 = *(const float2*)(bp + (size_t)2 * ldb);  rb3 = *(const float2*)(bp + (size_t)3 * ldb);
            rb4 = *(const float2*)(bp + (size_t)4 * ldb);  rb5 = *(const float2*)(bp + (size_t)5 * ldb);
            rb6 = *(const float2*)(bp + (size_t)6 * ldb);  rb7 = *(const float2*)(bp + (size_t)7 * ldb);
        } else {
            const float* bp = bptr + koff;
            rt0 = *(const float4*)(bp);     rt1 = *(const float4*)(bp + 4);
            rt2 = *(const float4*)(bp + 8); rt3 = *(const float4*)(bp + 12);
        }
    };
    auto STORE_LDS = [&](int buf) {
        unsigned short* ad = &As[buf][adoff];
        *(short8v*)(ad)      = ra0; *(short8v*)(ad + 8)  = ra1;
        *(short8v*)(ad + 16) = ra2; *(short8v*)(ad + 24) = ra3;
        if (!BT) {
            short8v s0, s1;
            s0[0]=(short)f2bf(rb0.x); s1[0]=(short)f2bf(rb0.y);
            s0[1]=(short)f2bf(rb1.x); s1[1]=(short)f2bf(rb1.y);
            s0[2]=(short)f2bf(rb2.x); s1[2]=(short)f2bf(rb2.y);
            s0[3]=(short)f2bf(rb3.x); s1[3]=(short)f2bf(rb3.y);
            s0[4]=(short)f2bf(rb4.x); s1[4]=(short)f2bf(rb4.y);
            s0[5]=(short)f2bf(rb5.x); s1[5]=(short)f2bf(rb5.y);
            s0[6]=(short)f2bf(rb6.x); s1[6]=(short)f2bf(rb6.y);
            s0[7]=(short)f2bf(rb7.x); s1[7]=(short)f2bf(rb7.y);
            *(short8v*)(&Bs[buf][(bnp * 2 + 0) * 72 + bkc * 8]) = s0;
            *(short8v*)(&Bs[buf][(bnp * 2 + 1) * 72 + bkc * 8]) = s1;
        } else {
            short8v s0, s1;
            s0[0]=(short)f2bf(rt0.x); s0[1]=(short)f2bf(rt0.y); s0[2]=(short)f2bf(rt0.z); s0[3]=(short)f2bf(rt0.w);
            s0[4]=(short)f2bf(rt1.x); s0[5]=(short)f2bf(rt1.y); s0[6]=(short)f2bf(rt1.z); s0[7]=(short)f2bf(rt1.w);
            s1[0]=(short)f2bf(rt2.x); s1[1]=(short)f2bf(rt2.y); s1[2]=(short)f2bf(rt2.z); s1[3]=(short)f2bf(rt2.w);
            s1[4]=(short)f2bf(rt3.x); s1[5]=(short)f2bf(rt3.y); s1[6]=(short)f2bf(rt3.z); s1[7]=(short)f2bf(rt3.w);
            *(short8v*)(&Bs[buf][bnr * 72 + bpart * 16])     = s0;
            *(short8v*)(&Bs[buf][bnr * 72 + bpart * 16 + 8]) = s1;
        }
    };

    const int nsteps = kchunk >> 6;
    LOAD(0);
    STORE_LDS(0);
    if (nsteps > 1) LOAD(1);
    __syncthreads();

    for (int kk = 0; kk < nsteps; ++kk) {
        // write tile kk+1 into the alternate buffer (regs loaded a full iter ago)
        if (kk + 1 < nsteps) STORE_LDS((kk + 1) & 1);
        // issue loads for tile kk+2 (land during next iteration)
        if (kk + 2 < nsteps) LOAD(kk + 2);
        // MFMA on tile kk
        const unsigned short* Ab = &As[kk & 1][0];
        const unsigned short* Bb = &Bs[kk & 1][0];
        #pragma unroll
        for (int ks = 0; ks < 64; ks += 32) {
            bf16x8 af[4], bfv[2];
            #pragma unroll
            for (int mt = 0; mt < 4; ++mt)
                af[mt] = __builtin_bit_cast(bf16x8,
                    *(const short8v*)(Ab + (wm * 64 + mt * 16 + c16) * 72 + ks + q * 8));
            #pragma unroll
            for (int nt = 0; nt < 2; ++nt)
                bfv[nt] = __builtin_bit_cast(bf16x8,
                    *(const short8v*)(Bb + (wn * 32 + nt * 16 + c16) * 72 + ks + q * 8));
            #pragma unroll
            for (int mt = 0; mt < 4; ++mt)
                #pragma unroll
                for (int nt = 0; nt < 2; ++nt)
                    acc[mt][nt] = __builtin_amdgcn_mfma_f32_16x16x32_bf16(
                        af[mt], bfv[nt], acc[mt][nt], 0, 0, 0);
        }
        if (kk + 1 < nsteps) __syncthreads();
    }
    // ---- store (D frag: col = lane&15, row = (lane>>4)*4 + j)
    #pragma unroll
    for (int mt = 0; mt < 4; ++mt) {
        const int m = wm * 64 + mt * 16 + q * 4;
        #pragma unroll
        for (int nt = 0; nt < 2; ++nt) {
            const int n = n0 + wn * 32 + nt * 16 + c16;
            const float bb = bias ? bias[n] : 0.0f;
            #pragma unroll
            for (int j = 0; j < 4; ++j)
                C[(size_t)(m + j) * ldc + n] = acc[mt][nt][j] + bb;
        }
    }
}

// GEMM1 (c@W1) and GEMM3 (x@base_down) in one launch: grid (16, 8, 2)
__global__ __launch_bounds__(256, 2) void gemm13_kernel(
    const unsigned short* __restrict__ cbf, const float* __restrict__ W1, float* __restrict__ P1,
    const unsigned short* __restrict__ xbf, const float* __restrict__ bdn, float* __restrict__ P2)
{
    const unsigned short* A = blockIdx.z ? xbf : cbf;
    const float* B = blockIdx.z ? bdn : W1;
    float* C = (blockIdx.z ? P2 : P1) + blockIdx.y * 131072;
    gemm_body<false>(A, B, C, nullptr, 1024, 1024, 128, blockIdx.y * 128, blockIdx.x * 64);
}

// GEMM2: w = h @ W2 + b2, direct store, grid (512)
__global__ __launch_bounds__(256, 2) void gemm2_kernel(
    const unsigned short* __restrict__ hbf, const float* __restrict__ W2,
    float* __restrict__ w, const float* __restrict__ b2)
{
    gemm_body<false>(hbf, W2, w, b2, 32768, 32768, 1024, 0, blockIdx.x * 64);
}

// GEMM4: partials of y @ base_up^T, split-K 16, grid (16, 16)
__global__ __launch_bounds__(256, 2) void gemm4_kernel(
    const unsigned short* __restrict__ ybf, const float* __restrict__ bup, float* __restrict__ P1)
{
    gemm_body<true>(ybf, bup, P1 + blockIdx.y * 131072, nullptr, 1024, 1024, 64, blockIdx.y * 64, blockIdx.x * 64);
}

// ---------- h = bf16(gelu(sum partials + b1)) ----------
__global__ __launch_bounds__(256) void hgen_kernel(
    const float* __restrict__ P, const float* __restrict__ bias, unsigned short* __restrict__ hbf)
{
    int idx = blockIdx.x * 256 + threadIdx.x;
    float s = bias[idx & 1023];
    #pragma unroll
    for (int p = 0; p < 8; ++p) s += P[p * 131072 + idx];
    hbf[idx] = f2bf(gelu_exact(s));
}

// ---------- per-row fused epilogue: t2, y=gelu(.), ybf, t1, out_init ----------
__device__ __forceinline__ void block_reduce8(float a[8], float* out8, float (*scr)[8], int t) {
    #pragma unroll
    for (int r = 0; r < 8; ++r)
        #pragma unroll
        for (int off = 32; off; off >>= 1)
            a[r] += __shfl_xor(a[r], off);
    if ((t & 63) == 0) {
        #pragma unroll
        for (int r = 0; r < 8; ++r) scr[t >> 6][r] = a[r];
    }
    __syncthreads();
    if (t < 8) out8[t] = scr[0][t] + scr[1][t] + scr[2][t] + scr[3][t];
    __syncthreads();
}

__global__ __launch_bounds__(256) void e1big_kernel(
    const float* __restrict__ P2, const float* __restrict__ w,
    const float* __restrict__ x, unsigned short* __restrict__ ybf,
    float* __restrict__ out)
{
    __shared__ float scr[4][8];
    __shared__ float t2s[8], t1s[8];
    const int b = blockIdx.x, t = threadIdx.x;
    const float* wrow = w + (size_t)b * 32768;
    const float* xrow = x + b * 1024;

    // stage 1: t2[r] = sum_d la2[b,d,r] * x[b,d]   (la2 = chunk 2 @ +16384)
    float a[8] = {0,0,0,0,0,0,0,0};
    #pragma unroll
    for (int i = 0; i < 4; ++i) {
        int d = t + i * 256;
        float xv = xrow[d];
        float4 w0 = *(const float4*)(wrow + 16384 + d * 8);
        float4 w1 = *(const float4*)(wrow + 16384 + d * 8 + 4);
        a[0] += xv * w0.x; a[1] += xv * w0.y; a[2] += xv * w0.z; a[3] += xv * w0.w;
        a[4] += xv * w1.x; a[5] += xv * w1.y; a[6] += xv * w1.z; a[7] += xv * w1.w;
    }
    block_reduce8(a, t2s, scr, t);
    float t2v[8];
    #pragma unroll
    for (int r = 0; r < 8; ++r) t2v[r] = t2s[r];

    // stage 2: y = gelu(sum P2 + lb2 @ t2); accumulate t1 = sum_l lb1[l,:]*y[l]
    float a1[8] = {0,0,0,0,0,0,0,0};
    #pragma unroll
    for (int i = 0; i < 4; ++i) {
        int l = t + i * 256;
        float s = 0.0f;
        #pragma unroll
        for (int p = 0; p < 8; ++p) s += P2[p * 131072 + b * 1024 + l];
        float4 w0 = *(const float4*)(wrow + 24576 + l * 8);
        float4 w1 = *(const float4*)(wrow + 24576 + l * 8 + 4);
        s += w0.x*t2v[0] + w0.y*t2v[1] + w0.z*t2v[2] + w0.w*t2v[3]
           + w1.x*t2v[4] + w1.y*t2v[5] + w1.z*t2v[6] + w1.w*t2v[7];
        float y = gelu_exact(s);
        ybf[b * 1024 + l] = f2bf(y);
        float4 l0 = *(const float4*)(wrow + 8192 + l * 8);
        float4 l1 = *(const float4*)(wrow + 8192 + l * 8 + 4);
        a1[0] += y * l0.x; a1[1] += y * l0.y; a1[2] += y * l0.z; a1[3] += y * l0.w;
        a1[4] += y * l1.x; a1[5] += y * l1.y; a1[6] += y * l1.z; a1[7] += y * l1.w;
    }
    block_reduce8(a1, t1s, scr, t);
    float t1v[8];
    #pragma unroll
    for (int r = 0; r < 8; ++r) t1v[r] = t1s[r];

    // stage 3: out_init = x + la1 @ t1   (la1 = chunk 0)
    #pragma unroll
    for (int i = 0; i < 4; ++i) {
        int k = t + i * 256;
        float4 w0 = *(const float4*)(wrow + k * 8);
        float4 w1 = *(const float4*)(wrow + k * 8 + 4);
        out[b * 1024 + k] = xrow[k]
           + w0.x*t1v[0] + w0.y*t1v[1] + w0.z*t1v[2] + w0.w*t1v[3]
           + w1.x*t1v[4] + w1.y*t1v[5] + w1.z*t1v[6] + w1.w*t1v[7];
    }
}

// ---------- out += sum GEMM4 partials (16 splits) ----------
__global__ __launch_bounds__(256) void e2f_kernel(
    const float* __restrict__ P1, float* __restrict__ out)
{
    int idx = blockIdx.x * 256 + threadIdx.x;
    float s = out[idx];
    #pragma unroll
    for (int p = 0; p < 16; ++p) s += P1[p * 131072 + idx];
    out[idx] = s;
}

extern "C" void kernel_launch(void* const* d_in, const int* in_sizes, int n_in,
                              void* d_out, int out_size, void* d_ws, size_t ws_size,
                              hipStream_t stream) {
    (void)in_sizes; (void)n_in; (void)out_size; (void)ws_size;
    const float* x        = (const float*)d_in[0];
    const float* ada      = (const float*)d_in[1];
    const float* base_up  = (const float*)d_in[2];
    const float* base_down= (const float*)d_in[3];
    const float* ln_g     = (const float*)d_in[4];
    const float* ln_b     = (const float*)d_in[5];
    const float* W1       = (const float*)d_in[6];
    const float* b1       = (const float*)d_in[7];
    const float* W2       = (const float*)d_in[8];
    const float* b2       = (const float*)d_in[9];

    char* ws = (char*)d_ws;
    float* w            = (float*)(ws + 0);          // 16 MiB
    float* P1           = (float*)(ws + 16777216);   // 8 MiB (16 split-K slabs; gemm1 uses 8)
    float* P2           = (float*)(ws + 25165824);   // 4 MiB
    unsigned short* cbf = (unsigned short*)(ws + 29360128); // 256 KiB
    unsigned short* xbf = (unsigned short*)(ws + 29622272);
    unsigned short* hbf = (unsigned short*)(ws + 29884416);
    unsigned short* ybf = (unsigned short*)(ws + 30146560);

    // 1. LN + bf16 casts
    ln_cast_kernel<<<128, 256, 0, stream>>>(ada, ln_g, ln_b, x, cbf, xbf);
    // 2. GEMM1 (c@W1 -> P1) + GEMM3 (x@base_down -> P2), split-K 8, one launch
    gemm13_kernel<<<dim3(16, 8, 2), 256, 0, stream>>>(cbf, W1, P1, xbf, base_down, P2);
    // 3. h = bf16(gelu(sum P1 + b1))
    hgen_kernel<<<512, 256, 0, stream>>>(P1, b1, hbf);
    // 4. GEMM2: w = h @ W2 + b2
    gemm2_kernel<<<512, 256, 0, stream>>>(hbf, W2, w, b2);
    // 5. fused row epilogue: t2, y, ybf, t1, out = x + la1@t1
    e1big_kernel<<<128, 256, 0, stream>>>(P2, w, x, ybf, (float*)d_out);
    // 6. GEMM4: partials of y @ base_up^T -> P1 (split-K 16)
    gemm4_kernel<<<dim3(16, 16), 256, 0, stream>>>(ybf, base_up, P1);
    // 7. out += sum partials
    e2f_kernel<<<512, 256, 0, stream>>>(P1, (float*)d_out);
}